// Round 1
// baseline (1524.531 us; speedup 1.0000x reference)
//
#include <hip/hip_runtime.h>

// ReEig via matrix-sign Newton-Schulz:
//   out = V max(D,eps) V^T = 0.5*(X + eps*I + |X - eps*I|),  |B| = B*sign(B)
// sign(B) computed by scaled Newton-Schulz (9 growth + 5 polish iterations),
// all as 64x64 fp32 matmuls in LDS. One 256-thread block per matrix.

constexpr int   LD    = 68;      // LDS row stride (floats): keeps float4 align, breaks bank conflicts
constexpr float EPS_  = 1e-4f;
constexpr int   GROW  = 9;       // scaled iterations: x <- g(1.5x), small-x gain 2.25x
constexpr int   POLISH= 5;       // plain NS: x <- g(x)

__device__ __forceinline__ void mm64(const float* __restrict__ A,
                                     const float* __restrict__ Bm,
                                     int ti, int tj, float acc[4][4]) {
    // C[i][j] = sum_k A[k][i] * Bm[k][j]  (= (A*Bm)[i][j] since A is symmetric)
#pragma unroll
    for (int r = 0; r < 4; ++r)
#pragma unroll
        for (int c = 0; c < 4; ++c) acc[r][c] = 0.f;

#pragma unroll 4
    for (int k = 0; k < 64; ++k) {
        const float4 a = *reinterpret_cast<const float4*>(&A [k * LD + 4 * ti]);
        const float4 b = *reinterpret_cast<const float4*>(&Bm[k * LD + 4 * tj]);
        const float ar[4] = {a.x, a.y, a.z, a.w};
        const float br[4] = {b.x, b.y, b.z, b.w};
#pragma unroll
        for (int r = 0; r < 4; ++r)
#pragma unroll
            for (int c = 0; c < 4; ++c)
                acc[r][c] = fmaf(ar[r], br[c], acc[r][c]);
    }
}

__global__ __launch_bounds__(256) void reeig_kernel(const float* __restrict__ in,
                                                    float* __restrict__ out) {
    __shared__ __align__(16) float Bs[64 * LD];
    __shared__ __align__(16) float Xs[64 * LD];
    __shared__ __align__(16) float Ws[64 * LD];
    __shared__ float red[4];

    const int tid = threadIdx.x;
    const int tj  = tid & 15;   // col group: cols 4*tj .. 4*tj+3
    const int ti  = tid >> 4;   // row group: rows 4*ti .. 4*ti+3
    const size_t base = (size_t)blockIdx.x * 4096;
    const float* __restrict__ src = in + base;
    float* __restrict__ dst = out + base;

    // ---- load B = X - eps*I into LDS, accumulate Frobenius norm^2 ----
    float4 v4[4];
    float frob = 0.f;
#pragma unroll
    for (int q = 0; q < 4; ++q) {
        const int idx4 = tid + 256 * q;        // coalesced float4 index
        const int lin  = idx4 << 2;
        const int r    = lin >> 6;
        const int c    = lin & 63;
        float4 v = reinterpret_cast<const float4*>(src)[idx4];
        const int d = r - c;                   // diagonal position within this float4 (0..3)
        v.x -= (d == 0) ? EPS_ : 0.f;
        v.y -= (d == 1) ? EPS_ : 0.f;
        v.z -= (d == 2) ? EPS_ : 0.f;
        v.w -= (d == 3) ? EPS_ : 0.f;
        v4[q] = v;
        frob += v.x * v.x + v.y * v.y + v.z * v.z + v.w * v.w;
        *reinterpret_cast<float4*>(&Bs[r * LD + c]) = v;
    }
    // block reduction (4 waves)
#pragma unroll
    for (int off = 32; off > 0; off >>= 1) frob += __shfl_down(frob, off);
    if ((tid & 63) == 0) red[tid >> 6] = frob;
    __syncthreads();
    const float tot = red[0] + red[1] + red[2] + red[3];
    const float inv = (tot > 0.f) ? rsqrtf(tot) : 0.f;

    // ---- X0 = B / ||B||_F ----
#pragma unroll
    for (int q = 0; q < 4; ++q) {
        const int idx4 = tid + 256 * q;
        const int lin  = idx4 << 2;
        const int r    = lin >> 6;
        const int c    = lin & 63;
        float4 v = v4[q];
        v.x *= inv; v.y *= inv; v.z *= inv; v.w *= inv;
        *reinterpret_cast<float4*>(&Xs[r * LD + c]) = v;
    }
    __syncthreads();

    // ---- Newton-Schulz iterations: X <- c1*X + c3*X^3 ----
    float acc[4][4];
    for (int it = 0; it < GROW + POLISH; ++it) {
        const bool  g  = (it < GROW);
        const float c1 = g ? 2.25f    : 1.5f;   // 1.5*t       (t=1.5 growth, t=1 polish)
        const float c3 = g ? -1.6875f : -0.5f;  // -0.5*t^3

        // W = c1*I + c3*(X^T X)   (X^T X exactly symmetric)
        mm64(Xs, Xs, ti, tj, acc);
#pragma unroll
        for (int r = 0; r < 4; ++r) {
            const int i = 4 * ti + r;
            float4 w;
            w.x = c3 * acc[r][0] + ((i == 4 * tj + 0) ? c1 : 0.f);
            w.y = c3 * acc[r][1] + ((i == 4 * tj + 1) ? c1 : 0.f);
            w.z = c3 * acc[r][2] + ((i == 4 * tj + 2) ? c1 : 0.f);
            w.w = c3 * acc[r][3] + ((i == 4 * tj + 3) ? c1 : 0.f);
            *reinterpret_cast<float4*>(&Ws[i * LD + 4 * tj]) = w;
        }
        __syncthreads();

        // Xnew = X * W
        mm64(Xs, Ws, ti, tj, acc);
        __syncthreads();   // all reads of Xs done before overwrite
#pragma unroll
        for (int r = 0; r < 4; ++r) {
            const int i = 4 * ti + r;
            float4 x;
            x.x = acc[r][0]; x.y = acc[r][1]; x.z = acc[r][2]; x.w = acc[r][3];
            *reinterpret_cast<float4*>(&Xs[i * LD + 4 * tj]) = x;
        }
        __syncthreads();
    }

    // ---- out = 0.5*(B + B*S) + eps*I ----
    mm64(Bs, Xs, ti, tj, acc);
#pragma unroll
    for (int r = 0; r < 4; ++r) {
        const int i = 4 * ti + r;
        float4 o;
        o.x = 0.5f * (acc[r][0] + Bs[i * LD + 4 * tj + 0]) + ((i == 4 * tj + 0) ? EPS_ : 0.f);
        o.y = 0.5f * (acc[r][1] + Bs[i * LD + 4 * tj + 1]) + ((i == 4 * tj + 1) ? EPS_ : 0.f);
        o.z = 0.5f * (acc[r][2] + Bs[i * LD + 4 * tj + 2]) + ((i == 4 * tj + 2) ? EPS_ : 0.f);
        o.w = 0.5f * (acc[r][3] + Bs[i * LD + 4 * tj + 3]) + ((i == 4 * tj + 3) ? EPS_ : 0.f);
        *reinterpret_cast<float4*>(&dst[i * 64 + 4 * tj]) = o;
    }
}

extern "C" void kernel_launch(void* const* d_in, const int* in_sizes, int n_in,
                              void* d_out, int out_size, void* d_ws, size_t ws_size,
                              hipStream_t stream) {
    const float* X = (const float*)d_in[0];
    float* O = (float*)d_out;
    const int batch = in_sizes[0] / 4096;   // 8192 matrices of 64x64
    reeig_kernel<<<batch, 256, 0, stream>>>(X, O);
}